// Round 2
// baseline (7045.388 us; speedup 1.0000x reference)
//
#include <hip/hip_runtime.h>
#include <stdint.h>

#define TT 2560
#define BB 64
#define CC 22
#define CP 24

typedef unsigned short ushort_t;
typedef __attribute__((ext_vector_type(4))) float floatx4;
typedef __attribute__((ext_vector_type(8))) short bf16x8;

__device__ __forceinline__ float bf2f(ushort_t u){
  union { uint32_t i; float f; } v; v.i = ((uint32_t)u) << 16; return v.f;
}
__device__ __forceinline__ ushort_t f2bf(float f){
  union { float f; uint32_t i; } v; v.f = f;
  uint32_t r = v.i + 0x7FFFu + ((v.i >> 16) & 1u);
  return (ushort_t)(r >> 16);
}
__device__ __forceinline__ float fsig(float x){ return 1.f/(1.f + __expf(-x)); }
__device__ __forceinline__ float ftanh(float x){ return 2.f/(1.f + __expf(-2.f*x)) - 1.f; }

// ---------------- K0a: transpose x [B][C][T] -> xT [B][T][CP] bf16 (pad c=22,23 with 0)
__global__ __launch_bounds__(256) void k_transpose_x(const float* __restrict__ x, ushort_t* __restrict__ xT){
  int idx = blockIdx.x*256 + threadIdx.x;           // 0 .. B*T-1
  if (idx >= BB*TT) return;
  int b = idx / TT, t = idx % TT;
  ushort_t* dst = xT + (size_t)idx*CP;
  const float* src = x + (size_t)b*CC*TT + t;
  #pragma unroll
  for (int c=0;c<CC;c++) dst[c] = f2bf(src[(size_t)c*TT]);
  dst[22] = 0; dst[23] = 0;
}

// ---------------- K0b: B0T[dir][n=512][k=160]: k<128 -> Wh0[k][n]; 128<=k<150 -> Wx0[k-128][n]; else 0
__global__ __launch_bounds__(256) void k_prep_l0(const float* __restrict__ WxF, const float* __restrict__ WhF,
                                                 const float* __restrict__ WxB, const float* __restrict__ WhB,
                                                 ushort_t* __restrict__ B0T){
  int idx = blockIdx.x*256 + threadIdx.x;
  if (idx >= 2*512*160) return;
  int dir = idx / 81920; int r = idx % 81920; int n = r / 160; int k = r % 160;
  const float* Wh = dir ? WhB : WhF;
  const float* Wx = dir ? WxB : WxF;
  float v = (k < 128) ? Wh[k*512 + n] : (((k-128) < CC) ? Wx[(k-128)*512 + n] : 0.f);
  B0T[idx] = f2bf(v);
}

// ---------------- K0c: B1T[dir][n=256][k=64] = Wh1[k][n]
__global__ __launch_bounds__(256) void k_prep_l1(const float* __restrict__ WhF, const float* __restrict__ WhB,
                                                 ushort_t* __restrict__ B1T){
  int idx = blockIdx.x*256 + threadIdx.x;
  if (idx >= 2*256*64) return;
  int dir = idx >> 14; int r = idx & 16383; int n = r >> 6; int k = r & 63;
  const float* Wh = dir ? WhB : WhF;
  B1T[idx] = f2bf(Wh[k*256 + n]);
}

// ---------------- K0d: WT[dir][n=256][k=256] = Wx1[k][n]  (for xz1 gemm)
__global__ __launch_bounds__(256) void k_prep_wxT(const float* __restrict__ Wf, const float* __restrict__ Wb,
                                                  ushort_t* __restrict__ WT){
  int idx = blockIdx.x*256 + threadIdx.x;
  int dir = idx >> 16; int r = idx & 65535; int n = r >> 8; int k = r & 255;
  const float* W = dir ? Wb : Wf;
  WT[idx] = f2bf(W[k*256 + n]);
}

// ---------------- K1: layer-0 MFMA scan. 16 chains (one dir) per WG, 8 waves.
__global__ __launch_bounds__(512, 2) void k_lstm0m(
  const ushort_t* __restrict__ xT, const ushort_t* __restrict__ B0T,
  const float* __restrict__ bF, const float* __restrict__ bB,
  ushort_t* __restrict__ h0seq)                     // [B][T][256]: fwd 0..127, bwd 128..255
{
  const int dir = blockIdx.x & 1, cb = blockIdx.x >> 1;
  const int tid = threadIdx.x;
  const int wv = tid >> 6, lane = tid & 63, m = lane & 15, q = lane >> 4;
  const int u = wv*16 + m;
  const float* bi = dir ? bB : bF;

  __shared__ ushort_t Abuf[2][16][168];             // [buf][chain][k: 0..127 h, 128..151 x, rest zero]

  bf16x8 Bf[4][5];                                  // resident weights, 80 VGPRs
  const ushort_t* Bb = B0T + (size_t)dir*512*160;
  #pragma unroll
  for (int nt=0; nt<4; nt++){
    int ntile = wv + nt*8;
    #pragma unroll
    for (int kt=0; kt<5; kt++)
      Bf[nt][kt] = *(const bf16x8*)(Bb + (size_t)(ntile*16+m)*160 + kt*32 + q*8);
  }
  float bias[4];
  #pragma unroll
  for (int g=0; g<4; g++) bias[g] = bi[g*128 + u];

  for (int i = tid; i < 2*16*168/2; i += 512) ((uint32_t*)Abuf)[i] = 0u;
  __syncthreads();

  int chain = 0, cx = 0; const ushort_t* xrow = nullptr;
  ushort_t xreg = 0, xreg2 = 0;
  if (tid < 16*CP){                                  // waves 0..5, no intra-wave divergence
    chain = tid / CP; cx = tid - chain*CP;
    xrow = xT + ((size_t)(cb*16 + chain)*TT)*CP + cx;
    int t0 = dir ? TT-1 : 0;
    int t1 = dir ? TT-2 : 1;
    int t2 = dir ? TT-3 : 2;
    Abuf[0][chain][128+cx] = xrow[(size_t)t0*CP];
    xreg  = xrow[(size_t)t1*CP];
    xreg2 = xrow[(size_t)t2*CP];
  }
  __syncthreads();

  float cst[4] = {0.f,0.f,0.f,0.f};
  size_t hb[4];
  #pragma unroll
  for (int r=0;r<4;r++)
    hb[r] = ((size_t)(cb*16 + q*4 + r)*TT)*256 + dir*128 + u;

  for (int s = 0; s < TT; ++s){
    const int cur = s & 1, nxt = cur ^ 1;
    const int t = dir ? (TT-1-s) : s;

    bf16x8 Af[5];
    const ushort_t* ar = &Abuf[cur][m][0];
    #pragma unroll
    for (int kt=0; kt<5; kt++) Af[kt] = *(const bf16x8*)(ar + kt*32 + q*8);

    floatx4 a0 = {bias[0],bias[0],bias[0],bias[0]};
    floatx4 a1 = {bias[1],bias[1],bias[1],bias[1]};
    floatx4 a2 = {bias[2],bias[2],bias[2],bias[2]};
    floatx4 a3 = {bias[3],bias[3],bias[3],bias[3]};
    #pragma unroll
    for (int kt=0; kt<5; kt++){
      a0 = __builtin_amdgcn_mfma_f32_16x16x32_bf16(Af[kt], Bf[0][kt], a0, 0,0,0);
      a1 = __builtin_amdgcn_mfma_f32_16x16x32_bf16(Af[kt], Bf[1][kt], a1, 0,0,0);
      a2 = __builtin_amdgcn_mfma_f32_16x16x32_bf16(Af[kt], Bf[2][kt], a2, 0,0,0);
      a3 = __builtin_amdgcn_mfma_f32_16x16x32_bf16(Af[kt], Bf[3][kt], a3, 0,0,0);
    }

    ushort_t xnew = 0;
    if (tid < 16*CP){                                // depth-2 prefetch
      int sn = s + 3; if (sn > TT-1) sn = TT-1;
      int tn = dir ? (TT-1-sn) : sn;
      xnew = xrow[(size_t)tn*CP];
    }

    #pragma unroll
    for (int r=0;r<4;r++){
      float ig = fsig(a0[r]);
      float fg = fsig(a1[r]);
      float gg = ftanh(a2[r]);
      float og = fsig(a3[r]);
      float cc = fg*cst[r] + ig*gg;
      cst[r] = cc;
      float h = og*ftanh(cc);
      ushort_t hv = f2bf(h);
      Abuf[nxt][q*4+r][u] = hv;
      h0seq[hb[r] + (size_t)t*256] = hv;
    }
    if (tid < 16*CP){
      Abuf[nxt][chain][128+cx] = xreg;
      xreg = xreg2; xreg2 = xnew;
    }
    __syncthreads();
  }
}

// ---------------- K2: xz1[dir][bt][256] = bf16( h0seq[bt][:256] @ Wx1[dir] )
__global__ __launch_bounds__(512) void k_xz1_gemm(const ushort_t* __restrict__ h0seq,
                                                  const ushort_t* __restrict__ WxT,
                                                  ushort_t* __restrict__ xz1)
{
  const int mb  = blockIdx.x;
  const int dir = blockIdx.y;
  const ushort_t* W   = WxT + (size_t)dir*256*256;
  ushort_t*       out = xz1 + (size_t)dir*BB*TT*256;
  const int wave = threadIdx.x >> 6;
  const int lane = threadIdx.x & 63;
  const int mw = wave & 3;
  const int nw = wave >> 2;
  const int m_ = lane & 15;
  const int q_ = lane >> 4;

  floatx4 acc[2][8];
  #pragma unroll
  for (int a=0;a<2;a++)
    #pragma unroll
    for (int n=0;n<8;n++) acc[a][n] = (floatx4)0.f;

  const size_t Abase = ((size_t)mb*128 + mw*32 + m_)*256 + q_*8;
  const size_t Bbase = ((size_t)nw*128 + m_)*256 + q_*8;

  for (int kc = 0; kc < 256; kc += 32){
    bf16x8 afr[2];
    #pragma unroll
    for (int mt=0;mt<2;mt++)
      afr[mt] = *(const bf16x8*)(h0seq + Abase + (size_t)mt*16*256 + kc);
    #pragma unroll
    for (int nt=0;nt<8;nt++){
      bf16x8 bfr = *(const bf16x8*)(W + Bbase + (size_t)nt*16*256 + kc);
      #pragma unroll
      for (int mt=0;mt<2;mt++)
        acc[mt][nt] = __builtin_amdgcn_mfma_f32_16x16x32_bf16(afr[mt], bfr, acc[mt][nt], 0,0,0);
    }
  }
  #pragma unroll
  for (int mt=0;mt<2;mt++)
    #pragma unroll
    for (int nt=0;nt<8;nt++)
      #pragma unroll
      for (int r=0;r<4;r++){
        size_t row = (size_t)mb*128 + mw*32 + mt*16 + q_*4 + r;
        int    col = nw*128 + nt*16 + m_;
        out[row*256 + col] = f2bf(acc[mt][nt][r]);
      }
}

// ---------------- K3: layer-1 MFMA scan. 16 chains per WG, 4 waves; only final h kept.
__global__ __launch_bounds__(256, 1) void k_lstm1m(
  const ushort_t* __restrict__ xz1,
  const ushort_t* __restrict__ B1T,
  const float* __restrict__ bF, const float* __restrict__ bB,
  float* __restrict__ h1last)
{
  const int dir = blockIdx.x & 1, cb = blockIdx.x >> 1;
  const int tid = threadIdx.x;
  const int wv = tid >> 6, lane = tid & 63, m = lane & 15, q = lane >> 4;
  const int u = wv*16 + m;
  const float* bi = dir ? bB : bF;

  __shared__ ushort_t Hbuf[2][16][72];
  __shared__ ushort_t XZbuf[2][16][264];

  bf16x8 Bf[4][2];
  const ushort_t* Bb = B1T + (size_t)dir*256*64;
  #pragma unroll
  for (int nt=0; nt<4; nt++){
    int ntile = wv + nt*4;
    #pragma unroll
    for (int kt=0; kt<2; kt++)
      Bf[nt][kt] = *(const bf16x8*)(Bb + (size_t)(ntile*16+m)*64 + kt*32 + q*8);
  }
  float bias[4];
  #pragma unroll
  for (int g=0; g<4; g++) bias[g] = bi[g*64 + u];

  for (int i = tid; i < 2*16*72/2; i += 256) ((uint32_t*)Hbuf)[i] = 0u;

  const int row = tid >> 4, cs = (tid & 15) * 16;
  const ushort_t* xzr = xz1 + (size_t)dir*BB*TT*256 + ((size_t)(cb*16+row)*TT)*256 + cs;
  uint4 pA0, pA1, pB0, pB1;
  {
    int t0 = dir ? TT-1 : 0;
    int t1 = dir ? TT-2 : 1;
    int t2 = dir ? TT-3 : 2;
    uint4 v0 = *(const uint4*)(xzr + (size_t)t0*256);
    uint4 v1 = *(const uint4*)(xzr + (size_t)t0*256 + 8);
    *(uint4*)&XZbuf[0][row][cs]   = v0;
    *(uint4*)&XZbuf[0][row][cs+8] = v1;
    pA0 = *(const uint4*)(xzr + (size_t)t1*256);
    pA1 = *(const uint4*)(xzr + (size_t)t1*256 + 8);
    pB0 = *(const uint4*)(xzr + (size_t)t2*256);
    pB1 = *(const uint4*)(xzr + (size_t)t2*256 + 8);
  }
  __syncthreads();

  float cst[4] = {0.f,0.f,0.f,0.f};
  float hreg[4] = {0.f,0.f,0.f,0.f};

  for (int s = 0; s < TT; ++s){
    const int cur = s & 1, nxt = cur ^ 1;

    bf16x8 Af[2];
    const ushort_t* ar = &Hbuf[cur][m][0];
    Af[0] = *(const bf16x8*)(ar + q*8);
    Af[1] = *(const bf16x8*)(ar + 32 + q*8);

    floatx4 a0 = {bias[0],bias[0],bias[0],bias[0]};
    floatx4 a1 = {bias[1],bias[1],bias[1],bias[1]};
    floatx4 a2 = {bias[2],bias[2],bias[2],bias[2]};
    floatx4 a3 = {bias[3],bias[3],bias[3],bias[3]};
    #pragma unroll
    for (int kt=0; kt<2; kt++){
      a0 = __builtin_amdgcn_mfma_f32_16x16x32_bf16(Af[kt], Bf[0][kt], a0, 0,0,0);
      a1 = __builtin_amdgcn_mfma_f32_16x16x32_bf16(Af[kt], Bf[1][kt], a1, 0,0,0);
      a2 = __builtin_amdgcn_mfma_f32_16x16x32_bf16(Af[kt], Bf[2][kt], a2, 0,0,0);
      a3 = __builtin_amdgcn_mfma_f32_16x16x32_bf16(Af[kt], Bf[3][kt], a3, 0,0,0);
    }

    *(uint4*)&XZbuf[nxt][row][cs]   = pA0;
    *(uint4*)&XZbuf[nxt][row][cs+8] = pA1;
    pA0 = pB0; pA1 = pB1;
    {
      int sn = s + 3; if (sn > TT-1) sn = TT-1;
      int tn = dir ? (TT-1-sn) : sn;
      pB0 = *(const uint4*)(xzr + (size_t)tn*256);
      pB1 = *(const uint4*)(xzr + (size_t)tn*256 + 8);
    }

    #pragma unroll
    for (int r=0;r<4;r++){
      int ci = q*4 + r;
      float zi = a0[r] + bf2f(XZbuf[cur][ci][u]);
      float zf = a1[r] + bf2f(XZbuf[cur][ci][64 + u]);
      float zg = a2[r] + bf2f(XZbuf[cur][ci][128 + u]);
      float zo = a3[r] + bf2f(XZbuf[cur][ci][192 + u]);
      float ig = fsig(zi), fg = fsig(zf), og = fsig(zo);
      float gg = ftanh(zg);
      float cc = fg*cst[r] + ig*gg;
      cst[r] = cc;
      float h = og*ftanh(cc);
      hreg[r] = h;
      Hbuf[nxt][ci][u] = f2bf(h);
    }
    __syncthreads();
  }
  #pragma unroll
  for (int r=0;r<4;r++)
    h1last[(size_t)(cb*16 + q*4 + r)*128 + dir*64 + u] = hreg[r];
}

// ---------------- K4: dense head
__global__ __launch_bounds__(128) void k_head(
  const float* __restrict__ h1last,
  const float* __restrict__ d0W, const float* __restrict__ d0b,
  const float* __restrict__ d1W, const float* __restrict__ d1b,
  const float* __restrict__ oW,  const float* __restrict__ ob,
  float* __restrict__ outp)
{
  const int b = blockIdx.x;
  const int j = threadIdx.x;
  __shared__ float v0[128], v1[128];
  v0[j] = h1last[b*128 + j];
  __syncthreads();
  float acc = d0b[j];
  #pragma unroll
  for (int k=0;k<128;k++) acc += v0[k]*d0W[k*128 + j];
  v1[j] = fmaxf(acc, 0.f);
  __syncthreads();
  if (j < 64){
    float a2 = d1b[j];
    #pragma unroll
    for (int k=0;k<128;k++) a2 += v1[k]*d1W[k*64 + j];
    float p = fmaxf(a2, 0.f) * oW[j];
    #pragma unroll
    for (int off=32; off>0; off>>=1) p += __shfl_down(p, off, 64);
    if (j == 0) outp[b] = 1.f/(1.f + __expf(-(p + ob[0])));
  }
}

extern "C" void kernel_launch(void* const* d_in, const int* in_sizes, int n_in,
                              void* d_out, int out_size, void* d_ws, size_t ws_size,
                              hipStream_t stream)
{
  const float* x     = (const float*)d_in[0];
  const float* l0fWx = (const float*)d_in[1];
  const float* l0fWh = (const float*)d_in[2];
  const float* l0fb  = (const float*)d_in[3];
  const float* l0bWx = (const float*)d_in[4];
  const float* l0bWh = (const float*)d_in[5];
  const float* l0bb  = (const float*)d_in[6];
  const float* l1fWx = (const float*)d_in[7];
  const float* l1fWh = (const float*)d_in[8];
  const float* l1fb  = (const float*)d_in[9];
  const float* l1bWx = (const float*)d_in[10];
  const float* l1bWh = (const float*)d_in[11];
  const float* l1bb  = (const float*)d_in[12];
  const float* d0W = (const float*)d_in[13];
  const float* d0b = (const float*)d_in[14];
  const float* d1W = (const float*)d_in[15];
  const float* d1b = (const float*)d_in[16];
  const float* oW  = (const float*)d_in[17];
  const float* ob  = (const float*)d_in[18];
  float* outp = (float*)d_out;

  char* ws = (char*)d_ws;
  const size_t OFF_XT  = 0;                        // 7,864,320
  const size_t OFF_H0  = OFF_XT  + 7864320ull;     // 83,886,080
  const size_t OFF_XZ  = OFF_H0  + 83886080ull;    // 167,772,160
  const size_t OFF_WT  = OFF_XZ  + 167772160ull;   // 262,144
  const size_t OFF_B0  = OFF_WT  + 262144ull;      // 327,680
  const size_t OFF_B1  = OFF_B0  + 327680ull;      // 65,536
  const size_t OFF_H1  = OFF_B1  + 65536ull;       // 32,768

  ushort_t* xT  = (ushort_t*)(ws + OFF_XT);
  ushort_t* h0  = (ushort_t*)(ws + OFF_H0);
  ushort_t* xz1 = (ushort_t*)(ws + OFF_XZ);
  ushort_t* WT  = (ushort_t*)(ws + OFF_WT);
  ushort_t* B0T = (ushort_t*)(ws + OFF_B0);
  ushort_t* B1T = (ushort_t*)(ws + OFF_B1);
  float*    h1l = (float*)(ws + OFF_H1);

  hipLaunchKernelGGL(k_transpose_x, dim3(640), dim3(256), 0, stream, x, xT);
  hipLaunchKernelGGL(k_prep_l0,     dim3(640), dim3(256), 0, stream, l0fWx, l0fWh, l0bWx, l0bWh, B0T);
  hipLaunchKernelGGL(k_prep_l1,     dim3(128), dim3(256), 0, stream, l1fWh, l1bWh, B1T);
  hipLaunchKernelGGL(k_prep_wxT,    dim3(512), dim3(256), 0, stream, l1fWx, l1bWx, WT);
  hipLaunchKernelGGL(k_lstm0m,      dim3(8),   dim3(512), 0, stream, xT, B0T, l0fb, l0bb, h0);
  hipLaunchKernelGGL(k_xz1_gemm,    dim3(1280,2), dim3(512), 0, stream, h0, WT, xz1);
  hipLaunchKernelGGL(k_lstm1m,      dim3(8),   dim3(256), 0, stream, xz1, B1T, l1fb, l1bb, h1l);
  hipLaunchKernelGGL(k_head,        dim3(64),  dim3(128), 0, stream,
                     h1l, d0W, d0b, d1W, d1b, oW, ob, outp);
}

// Round 3
// 2970.523 us; speedup vs baseline: 2.3718x; 2.3718x over previous
//
#include <hip/hip_runtime.h>
#include <stdint.h>

#define TT 2560
#define BB 64
#define CC 22
#define CP 24

typedef unsigned short ushort_t;
typedef __attribute__((ext_vector_type(4))) float floatx4;
typedef __attribute__((ext_vector_type(8))) short bf16x8;

__device__ __forceinline__ float bf2f(ushort_t u){
  union { uint32_t i; float f; } v; v.i = ((uint32_t)u) << 16; return v.f;
}
__device__ __forceinline__ ushort_t f2bf(float f){
  union { float f; uint32_t i; } v; v.f = f;
  uint32_t r = v.i + 0x7FFFu + ((v.i >> 16) & 1u);
  return (ushort_t)(r >> 16);
}
__device__ __forceinline__ float fsig(float x){ return 1.f/(1.f + __expf(-x)); }
__device__ __forceinline__ float ftanh(float x){ return 2.f/(1.f + __expf(-2.f*x)) - 1.f; }

// barrier that does NOT drain vmcnt: LDS-visibility only. Global stores and
// prefetch loads stay in flight across steps (the round-2 4ms stall was the
// implicit vmcnt(0) in __syncthreads inside the 2560-step serial loop).
__device__ __forceinline__ void ldsbar(){
  asm volatile("s_waitcnt lgkmcnt(0)\n\ts_barrier" ::: "memory");
}

// ---------------- K0a: transpose x [B][C][T] -> xT [B][T][CP] bf16 (pad c=22,23 with 0)
__global__ __launch_bounds__(256) void k_transpose_x(const float* __restrict__ x, ushort_t* __restrict__ xT){
  int idx = blockIdx.x*256 + threadIdx.x;
  if (idx >= BB*TT) return;
  int b = idx / TT, t = idx % TT;
  ushort_t* dst = xT + (size_t)idx*CP;
  const float* src = x + (size_t)b*CC*TT + t;
  #pragma unroll
  for (int c=0;c<CC;c++) dst[c] = f2bf(src[(size_t)c*TT]);
  dst[22] = 0; dst[23] = 0;
}

// ---------------- K0b: B0T[dir][n=512][k=160]: k<128 -> Wh0[k][n]; 128<=k<150 -> Wx0[k-128][n]; else 0
__global__ __launch_bounds__(256) void k_prep_l0(const float* __restrict__ WxF, const float* __restrict__ WhF,
                                                 const float* __restrict__ WxB, const float* __restrict__ WhB,
                                                 ushort_t* __restrict__ B0T){
  int idx = blockIdx.x*256 + threadIdx.x;
  if (idx >= 2*512*160) return;
  int dir = idx / 81920; int r = idx % 81920; int n = r / 160; int k = r % 160;
  const float* Wh = dir ? WhB : WhF;
  const float* Wx = dir ? WxB : WxF;
  float v = (k < 128) ? Wh[k*512 + n] : (((k-128) < CC) ? Wx[(k-128)*512 + n] : 0.f);
  B0T[idx] = f2bf(v);
}

// ---------------- K0c: B1T[dir][n=256][k=64] = Wh1[k][n]
__global__ __launch_bounds__(256) void k_prep_l1(const float* __restrict__ WhF, const float* __restrict__ WhB,
                                                 ushort_t* __restrict__ B1T){
  int idx = blockIdx.x*256 + threadIdx.x;
  if (idx >= 2*256*64) return;
  int dir = idx >> 14; int r = idx & 16383; int n = r >> 6; int k = r & 63;
  const float* Wh = dir ? WhB : WhF;
  B1T[idx] = f2bf(Wh[k*256 + n]);
}

// ---------------- K0d: WT[dir][n=256][k=256] = Wx1[k][n]  (for xz1 gemm)
__global__ __launch_bounds__(256) void k_prep_wxT(const float* __restrict__ Wf, const float* __restrict__ Wb,
                                                  ushort_t* __restrict__ WT){
  int idx = blockIdx.x*256 + threadIdx.x;
  int dir = idx >> 16; int r = idx & 65535; int n = r >> 8; int k = r & 255;
  const float* W = dir ? Wb : Wf;
  WT[idx] = f2bf(W[k*256 + n]);
}

// ---------------- K1: layer-0 MFMA scan. 4 chains/WG at C-rows {0,4,8,12} -> 32 WGs.
// Lane (q = lane>>4) owns chain q; acc reg[0] of each gate-acc is its z value.
__global__ __launch_bounds__(512, 1) void k_lstm0m(
  const ushort_t* __restrict__ xT, const ushort_t* __restrict__ B0T,
  const float* __restrict__ bF, const float* __restrict__ bB,
  ushort_t* __restrict__ h0seq)                     // [B][T][256]: fwd 0..127, bwd 128..255
{
  const int dir = blockIdx.x & 1, cb = blockIdx.x >> 1;   // cb 0..15, 4 batches each
  const int tid = threadIdx.x;
  const int wv = tid >> 6, lane = tid & 63, m = lane & 15, q = lane >> 4;
  const int u = wv*16 + m;                                // unit 0..127
  const float* bi = dir ? bB : bF;

  __shared__ ushort_t Abuf[2][16][168];   // rows {0,4,8,12}: [h(0..127) | x(128..151) | 0]; 336B row = 16B aligned

  bf16x8 Bf[4][5];                        // resident weights (80 VGPR): gate g = n-tile wv+8g
  const ushort_t* Bb = B0T + (size_t)dir*512*160;
  #pragma unroll
  for (int g=0; g<4; g++){
    int ntile = wv + g*8;
    #pragma unroll
    for (int kt=0; kt<5; kt++)
      Bf[g][kt] = *(const bf16x8*)(Bb + (size_t)(ntile*16+m)*160 + kt*32 + q*8);
  }
  const float b0 = bi[u], b1 = bi[128+u], b2 = bi[256+u], b3 = bi[384+u];

  for (int i = tid; i < 2*16*168*2/4; i += 512) ((uint32_t*)Abuf)[i] = 0u;
  __syncthreads();

  int chain = 0, cx = 0; const ushort_t* xrow = nullptr;
  ushort_t xreg = 0, xreg2 = 0;
  if (tid < 4*CP){
    chain = tid / CP; cx = tid - chain*CP;
    xrow = xT + ((size_t)(cb*4 + chain)*TT)*CP + cx;
    int t0 = dir ? TT-1 : 0;
    int t1 = dir ? TT-2 : 1;
    int t2 = dir ? TT-3 : 2;
    Abuf[0][chain*4][128+cx] = xrow[(size_t)t0*CP];
    xreg  = xrow[(size_t)t1*CP];
    xreg2 = xrow[(size_t)t2*CP];
  }
  __syncthreads();

  float cst = 0.f;
  const size_t hb = ((size_t)(cb*4 + q)*TT)*256 + (size_t)dir*128 + u;

  for (int s = 0; s < TT; ++s){
    const int cur = s & 1, nxt = cur ^ 1;
    const int t = dir ? (TT-1-s) : s;

    bf16x8 Af[5];
    const ushort_t* ar = &Abuf[cur][m][0];
    #pragma unroll
    for (int kt=0; kt<5; kt++) Af[kt] = *(const bf16x8*)(ar + kt*32 + q*8);

    floatx4 a0 = (floatx4)0.f, a1 = (floatx4)0.f, a2 = (floatx4)0.f, a3 = (floatx4)0.f;
    #pragma unroll
    for (int kt=0; kt<5; kt++){
      a0 = __builtin_amdgcn_mfma_f32_16x16x32_bf16(Af[kt], Bf[0][kt], a0, 0,0,0);
      a1 = __builtin_amdgcn_mfma_f32_16x16x32_bf16(Af[kt], Bf[1][kt], a1, 0,0,0);
      a2 = __builtin_amdgcn_mfma_f32_16x16x32_bf16(Af[kt], Bf[2][kt], a2, 0,0,0);
      a3 = __builtin_amdgcn_mfma_f32_16x16x32_bf16(Af[kt], Bf[3][kt], a3, 0,0,0);
    }

    ushort_t xnew = 0;
    if (tid < 4*CP){                      // depth-2 x prefetch (never drained at barrier)
      int sn = s + 3; if (sn > TT-1) sn = TT-1;
      int tn = dir ? (TT-1-sn) : sn;
      xnew = xrow[(size_t)tn*CP];
    }

    // one gate-set per lane: chain q (C-row 4q, reg 0)
    {
      float ig = fsig(a0[0] + b0);
      float fg = fsig(a1[0] + b1);
      float gg = ftanh(a2[0] + b2);
      float og = fsig(a3[0] + b3);
      float cc = fg*cst + ig*gg;
      cst = cc;
      float h = og*ftanh(cc);
      ushort_t hv = f2bf(h);
      Abuf[nxt][q*4][u] = hv;
      h0seq[hb + (size_t)t*256] = hv;     // fire-and-forget
    }
    if (tid < 4*CP){
      Abuf[nxt][chain*4][128+cx] = xreg;
      xreg = xreg2; xreg2 = xnew;
    }
    ldsbar();
  }
}

// ---------------- K2: xz1[dir][bt][256] = bf16( h0seq[bt][:256] @ Wx1[dir] )
__global__ __launch_bounds__(512) void k_xz1_gemm(const ushort_t* __restrict__ h0seq,
                                                  const ushort_t* __restrict__ WxT,
                                                  ushort_t* __restrict__ xz1)
{
  const int mb  = blockIdx.x;
  const int dir = blockIdx.y;
  const ushort_t* W   = WxT + (size_t)dir*256*256;
  ushort_t*       out = xz1 + (size_t)dir*BB*TT*256;
  const int wave = threadIdx.x >> 6;
  const int lane = threadIdx.x & 63;
  const int mw = wave & 3;
  const int nw = wave >> 2;
  const int m_ = lane & 15;
  const int q_ = lane >> 4;

  floatx4 acc[2][8];
  #pragma unroll
  for (int a=0;a<2;a++)
    #pragma unroll
    for (int n=0;n<8;n++) acc[a][n] = (floatx4)0.f;

  const size_t Abase = ((size_t)mb*128 + mw*32 + m_)*256 + q_*8;
  const size_t Bbase = ((size_t)nw*128 + m_)*256 + q_*8;

  for (int kc = 0; kc < 256; kc += 32){
    bf16x8 afr[2];
    #pragma unroll
    for (int mt=0;mt<2;mt++)
      afr[mt] = *(const bf16x8*)(h0seq + Abase + (size_t)mt*16*256 + kc);
    #pragma unroll
    for (int nt=0;nt<8;nt++){
      bf16x8 bfr = *(const bf16x8*)(W + Bbase + (size_t)nt*16*256 + kc);
      #pragma unroll
      for (int mt=0;mt<2;mt++)
        acc[mt][nt] = __builtin_amdgcn_mfma_f32_16x16x32_bf16(afr[mt], bfr, acc[mt][nt], 0,0,0);
    }
  }
  #pragma unroll
  for (int mt=0;mt<2;mt++)
    #pragma unroll
    for (int nt=0;nt<8;nt++)
      #pragma unroll
      for (int r=0;r<4;r++){
        size_t row = (size_t)mb*128 + mw*32 + mt*16 + q_*4 + r;
        int    col = nw*128 + nt*16 + m_;
        out[row*256 + col] = f2bf(acc[mt][nt][r]);
      }
}

// ---------------- K3: layer-1 MFMA scan. 4 chains/WG at C-rows {0,4,8,12} -> 32 WGs, 4 waves.
__global__ __launch_bounds__(256, 1) void k_lstm1m(
  const ushort_t* __restrict__ xz1,                 // [dir][b*T+t][256] bf16
  const ushort_t* __restrict__ B1T,                 // [dir][n=256][k=64] bf16
  const float* __restrict__ bF, const float* __restrict__ bB,
  float* __restrict__ h1last)                       // [B][128]: fwd 0..63, bwd 64..127
{
  const int dir = blockIdx.x & 1, cb = blockIdx.x >> 1;   // cb 0..15
  const int tid = threadIdx.x;
  const int wv = tid >> 6, lane = tid & 63, m = lane & 15, q = lane >> 4;
  const int u = wv*16 + m;                                // unit 0..63
  const float* bi = dir ? bB : bF;

  __shared__ ushort_t Hbuf[2][16][88];    // 176B rows, 16B aligned
  __shared__ ushort_t XZbuf[2][4][264];

  bf16x8 Bf[4][2];                        // gate g = n-tile wv+4g
  const ushort_t* Bb = B1T + (size_t)dir*256*64;
  #pragma unroll
  for (int g=0; g<4; g++){
    int ntile = wv + g*4;
    #pragma unroll
    for (int kt=0; kt<2; kt++)
      Bf[g][kt] = *(const bf16x8*)(Bb + (size_t)(ntile*16+m)*64 + kt*32 + q*8);
  }
  const float b0 = bi[u], b1 = bi[64+u], b2 = bi[128+u], b3 = bi[192+u];

  for (int i = tid; i < 2*16*88*2/4; i += 256) ((uint32_t*)Hbuf)[i] = 0u;

  const int ch = tid >> 6;                // staging: chain ch, 64 lanes x 4 ushorts
  const int l  = tid & 63;
  const ushort_t* xzr = xz1 + (size_t)dir*BB*TT*256 + ((size_t)(cb*4+ch)*TT)*256 + l*4;
  uint2 pA, pB;
  {
    int t0 = dir ? TT-1 : 0;
    int t1 = dir ? TT-2 : 1;
    int t2 = dir ? TT-3 : 2;
    *(uint2*)&XZbuf[0][ch][l*4] = *(const uint2*)(xzr + (size_t)t0*256);
    pA = *(const uint2*)(xzr + (size_t)t1*256);
    pB = *(const uint2*)(xzr + (size_t)t2*256);
  }
  __syncthreads();

  float cst = 0.f, hlast = 0.f;

  for (int s = 0; s < TT; ++s){
    const int cur = s & 1, nxt = cur ^ 1;

    bf16x8 Af[2];
    const ushort_t* ar = &Hbuf[cur][m][0];
    Af[0] = *(const bf16x8*)(ar + q*8);
    Af[1] = *(const bf16x8*)(ar + 32 + q*8);

    floatx4 a0 = (floatx4)0.f, a1 = (floatx4)0.f, a2 = (floatx4)0.f, a3 = (floatx4)0.f;
    #pragma unroll
    for (int kt=0; kt<2; kt++){
      a0 = __builtin_amdgcn_mfma_f32_16x16x32_bf16(Af[kt], Bf[0][kt], a0, 0,0,0);
      a1 = __builtin_amdgcn_mfma_f32_16x16x32_bf16(Af[kt], Bf[1][kt], a1, 0,0,0);
      a2 = __builtin_amdgcn_mfma_f32_16x16x32_bf16(Af[kt], Bf[2][kt], a2, 0,0,0);
      a3 = __builtin_amdgcn_mfma_f32_16x16x32_bf16(Af[kt], Bf[3][kt], a3, 0,0,0);
    }

    // publish prefetched xz(s+1); issue load for s+3 (stays in flight across ldsbar)
    *(uint2*)&XZbuf[nxt][ch][l*4] = pA;
    pA = pB;
    {
      int sn = s + 3; if (sn > TT-1) sn = TT-1;
      int tn = dir ? (TT-1-sn) : sn;
      pB = *(const uint2*)(xzr + (size_t)tn*256);
    }

    {
      float zi = a0[0] + b0 + bf2f(XZbuf[cur][q][u]);
      float zf = a1[0] + b1 + bf2f(XZbuf[cur][q][64 + u]);
      float zg = a2[0] + b2 + bf2f(XZbuf[cur][q][128 + u]);
      float zo = a3[0] + b3 + bf2f(XZbuf[cur][q][192 + u]);
      float ig = fsig(zi), fg = fsig(zf), og = fsig(zo);
      float gg = ftanh(zg);
      float cc = fg*cst + ig*gg;
      cst = cc;
      hlast = og*ftanh(cc);
      Hbuf[nxt][q*4][u] = f2bf(hlast);
    }
    ldsbar();
  }
  h1last[(size_t)(cb*4 + q)*128 + dir*64 + u] = hlast;
}

// ---------------- K4: dense head
__global__ __launch_bounds__(128) void k_head(
  const float* __restrict__ h1last,
  const float* __restrict__ d0W, const float* __restrict__ d0b,
  const float* __restrict__ d1W, const float* __restrict__ d1b,
  const float* __restrict__ oW,  const float* __restrict__ ob,
  float* __restrict__ outp)
{
  const int b = blockIdx.x;
  const int j = threadIdx.x;
  __shared__ float v0[128], v1[128];
  v0[j] = h1last[b*128 + j];
  __syncthreads();
  float acc = d0b[j];
  #pragma unroll
  for (int k=0;k<128;k++) acc += v0[k]*d0W[k*128 + j];
  v1[j] = fmaxf(acc, 0.f);
  __syncthreads();
  if (j < 64){
    float a2 = d1b[j];
    #pragma unroll
    for (int k=0;k<128;k++) a2 += v1[k]*d1W[k*64 + j];
    float p = fmaxf(a2, 0.f) * oW[j];
    #pragma unroll
    for (int off=32; off>0; off>>=1) p += __shfl_down(p, off, 64);
    if (j == 0) outp[b] = 1.f/(1.f + __expf(-(p + ob[0])));
  }
}

extern "C" void kernel_launch(void* const* d_in, const int* in_sizes, int n_in,
                              void* d_out, int out_size, void* d_ws, size_t ws_size,
                              hipStream_t stream)
{
  const float* x     = (const float*)d_in[0];
  const float* l0fWx = (const float*)d_in[1];
  const float* l0fWh = (const float*)d_in[2];
  const float* l0fb  = (const float*)d_in[3];
  const float* l0bWx = (const float*)d_in[4];
  const float* l0bWh = (const float*)d_in[5];
  const float* l0bb  = (const float*)d_in[6];
  const float* l1fWx = (const float*)d_in[7];
  const float* l1fWh = (const float*)d_in[8];
  const float* l1fb  = (const float*)d_in[9];
  const float* l1bWx = (const float*)d_in[10];
  const float* l1bWh = (const float*)d_in[11];
  const float* l1bb  = (const float*)d_in[12];
  const float* d0W = (const float*)d_in[13];
  const float* d0b = (const float*)d_in[14];
  const float* d1W = (const float*)d_in[15];
  const float* d1b = (const float*)d_in[16];
  const float* oW  = (const float*)d_in[17];
  const float* ob  = (const float*)d_in[18];
  float* outp = (float*)d_out;

  char* ws = (char*)d_ws;
  const size_t OFF_XT  = 0;                        // 7,864,320
  const size_t OFF_H0  = OFF_XT  + 7864320ull;     // 83,886,080
  const size_t OFF_XZ  = OFF_H0  + 83886080ull;    // 167,772,160
  const size_t OFF_WT  = OFF_XZ  + 167772160ull;   // 262,144
  const size_t OFF_B0  = OFF_WT  + 262144ull;      // 327,680
  const size_t OFF_B1  = OFF_B0  + 327680ull;      // 65,536
  const size_t OFF_H1  = OFF_B1  + 65536ull;       // 32,768

  ushort_t* xT  = (ushort_t*)(ws + OFF_XT);
  ushort_t* h0  = (ushort_t*)(ws + OFF_H0);
  ushort_t* xz1 = (ushort_t*)(ws + OFF_XZ);
  ushort_t* WT  = (ushort_t*)(ws + OFF_WT);
  ushort_t* B0T = (ushort_t*)(ws + OFF_B0);
  ushort_t* B1T = (ushort_t*)(ws + OFF_B1);
  float*    h1l = (float*)(ws + OFF_H1);

  hipLaunchKernelGGL(k_transpose_x, dim3(640), dim3(256), 0, stream, x, xT);
  hipLaunchKernelGGL(k_prep_l0,     dim3(640), dim3(256), 0, stream, l0fWx, l0fWh, l0bWx, l0bWh, B0T);
  hipLaunchKernelGGL(k_prep_l1,     dim3(128), dim3(256), 0, stream, l1fWh, l1bWh, B1T);
  hipLaunchKernelGGL(k_prep_wxT,    dim3(512), dim3(256), 0, stream, l1fWx, l1bWx, WT);
  hipLaunchKernelGGL(k_lstm0m,      dim3(32),  dim3(512), 0, stream, xT, B0T, l0fb, l0bb, h0);
  hipLaunchKernelGGL(k_xz1_gemm,    dim3(1280,2), dim3(512), 0, stream, h0, WT, xz1);
  hipLaunchKernelGGL(k_lstm1m,      dim3(32),  dim3(256), 0, stream, xz1, B1T, l1fb, l1bb, h1l);
  hipLaunchKernelGGL(k_head,        dim3(64),  dim3(128), 0, stream,
                     h1l, d0W, d0b, d1W, d1b, oW, ob, outp);
}